// Round 7
// baseline (160.916 us; speedup 1.0000x reference)
//
#include <hip/hip_runtime.h>
#include <hip/hip_bf16.h>

// RBF kernel layer: out[n][m] = exp(-||x_n - c_m||^2)
// Round 7: INSTRUMENTED PROBE on the round-6 fp8 kernel. The GEMM runs the
// prologue+K-loop TWICE: pass 0 stages real x8, pass 1 stages an all-zero
// x8z through the identical path (MFMA adds exactly 0 -> output unchanged).
// dur_delta vs round 6 == cost of one full K-loop incl. staging; also pushes
// the GEMM above the harness's 150us fill dispatches so rocprof top-5 shows
// its counters. Everything else is byte-identical to round 6.

#define NN 16384
#define MM 4096
#define DD 512
#define NT 8  // K-tiles of BK=64

typedef float f32x4 __attribute__((ext_vector_type(4)));
typedef long i64x2 __attribute__((ext_vector_type(2)));

__device__ __forceinline__ void async16(const void* g, void* l) {
  __builtin_amdgcn_global_load_lds(
      (const __attribute__((address_space(1))) void*)g,
      (__attribute__((address_space(3))) void*)l, 16, 0, 0);
}

#define MFMA8(a, b, c) __builtin_amdgcn_mfma_f32_16x16x32_fp8_fp8(a, b, c, 0, 0, 0)

// ---------------------------------------------------------------------------
// Prep: fp32 row -> fp8 e4m3 (row bytes packed (kt, fq)-major) + exact fp32
// squared norm. x-rows additionally zero-fill the probe buffer x8z.
// ---------------------------------------------------------------------------
__global__ __launch_bounds__(256) void prep_fp8(
    const float* __restrict__ x, const float* __restrict__ c,
    unsigned char* __restrict__ x8, unsigned char* __restrict__ c8,
    unsigned char* __restrict__ x8z, float* __restrict__ xsq,
    float* __restrict__ csq) {
  const int w = threadIdx.x >> 6;
  const int lane = threadIdx.x & 63;
  int row = blockIdx.x * 4 + w;
  const float* src = x;
  unsigned char* dst = x8;
  float* sq = xsq;
  const int isx = (row < NN);
  if (!isx) {
    row -= NN;
    src = c; dst = c8; sq = csq;
    if (row >= MM) return;
  }
  const float* p = src + (size_t)row * DD + lane * 8;
  float4 v0 = *(const float4*)p;
  float4 v1 = *(const float4*)(p + 4);
  float vv[8] = {v0.x, v0.y, v0.z, v0.w, v1.x, v1.y, v1.z, v1.w};
  float s = 0.f;
#pragma unroll
  for (int j = 0; j < 8; ++j) s += vv[j] * vv[j];
  int pk0 = __builtin_amdgcn_cvt_pk_fp8_f32(vv[0], vv[1], 0, false);
  int pk1 = __builtin_amdgcn_cvt_pk_fp8_f32(vv[2], vv[3], 0, false);
  int pk2 = __builtin_amdgcn_cvt_pk_fp8_f32(vv[4], vv[5], 0, false);
  int pk3 = __builtin_amdgcn_cvt_pk_fp8_f32(vv[6], vv[7], 0, false);
  uint2 wrd;
  wrd.x = (unsigned)(pk0 & 0xFFFF) | ((unsigned)pk1 << 16);
  wrd.y = (unsigned)(pk2 & 0xFFFF) | ((unsigned)pk3 << 16);
  const int db = ((lane >> 3) << 6) + ((lane & 3) << 4) + (((lane >> 2) & 1) << 3);
  *(uint2*)(dst + (size_t)row * DD + db) = wrd;
  if (isx) *(uint2*)(x8z + (size_t)row * DD + db) = (uint2){0u, 0u};
#pragma unroll
  for (int o = 32; o >= 1; o >>= 1) s += __shfl_down(s, o);
  if (lane == 0) sq[row] = s;
}

// ---------------------------------------------------------------------------
// 256x256 8-phase fp8 GEMM, K-loop executed twice (pass 1 = zero data).
// Structure identical to round 6 (see round-6 comments for the FIFO audit).
// ---------------------------------------------------------------------------
__global__ __launch_bounds__(512, 2) void rbf_gemm(
    const unsigned char* __restrict__ x8, const unsigned char* __restrict__ c8,
    const unsigned char* __restrict__ x8z, const float* __restrict__ xsq,
    const float* __restrict__ csq, float* __restrict__ out) {
  __shared__ __attribute__((aligned(16))) unsigned char sX[2][16384];
  __shared__ __attribute__((aligned(16))) unsigned char sC[2][16384];

  const int t = threadIdx.x;
  const int w = t >> 6;
  const int lane = t & 63;
  const int fr = lane & 15;
  const int fq = lane >> 4;
  const int wr = w >> 2;  // x-row half (0..1)
  const int wc = w & 3;   // c-col quarter (0..3)

  const int bid = blockIdx.x;
  const int a = bid & 7, p = bid >> 3;
  const int x0 = ((a << 3) + (p >> 4)) << 8;
  const int c0 = (p & 15) << 8;

  // staging addressing (linear LDS dest, inverse-swizzled global source)
  const int w3 = w & 3;
  const int isX = (w < 4);
  const int rr = 2 * (lane >> 3) + ((lane >> 2) & 1);
  const int ff = (lane & 3) ^ ((lane >> 3) & 3);
  const size_t goff = (size_t)((isX ? x0 : c0) + 16 * w3 + rr) * DD + ff * 16;
  const unsigned char* gsrc0 = (isX ? x8 : c8) + goff;
  const unsigned char* gsrc1 = (isX ? x8z : c8) + goff;
  char* lbase = (isX ? (char*)sX : (char*)sC) + w3 * 1024;

#define STAGE(buf, i, kt) \
  async16(gsrc + (size_t)(i) * 64 * DD + (kt) * 64, \
          lbase + ((buf) << 14) + (i) * 4096)

  // ds_read addressing: byte = row*64 + 16*(fq ^ ((fr>>1)&3))
  const int sxor = (fq ^ ((fr >> 1) & 3)) << 4;
  const int rcb = (wc * 64 + fr) * 64;
  const int rxb = (wr * 128 + fr) * 64;

  f32x4 acc[8][4];
#pragma unroll
  for (int m = 0; m < 8; ++m)
#pragma unroll
    for (int n = 0; n < 4; ++n) acc[m][n] = (f32x4){0.f, 0.f, 0.f, 0.f};

#define DOMFMA(qq, mm)                                                   \
  _Pragma("unroll") for (int n = 0; n < 4; ++n) {                        \
    acc[2 * (qq) + (mm)][n] = MFMA8(cf[n][0], xq[mm][0], acc[2 * (qq) + (mm)][n]); \
    acc[2 * (qq) + (mm)][n] = MFMA8(cf[n][1], xq[mm][1], acc[2 * (qq) + (mm)][n]); \
  }

#pragma unroll 1
  for (int rep = 0; rep < 2; ++rep) {
    const unsigned char* gsrc = rep ? gsrc1 : gsrc0;

    // prologue: tile0 all 4 issues + tile1 XC0, XC2
    STAGE(0, 0, 0); STAGE(0, 1, 0); STAGE(0, 2, 0); STAGE(0, 3, 0);
    STAGE(1, 0, 1); STAGE(1, 2, 1);
    asm volatile("s_waitcnt vmcnt(2)" ::: "memory");
    __builtin_amdgcn_s_barrier();
    __builtin_amdgcn_sched_barrier(0);

#pragma unroll 1
    for (int u = 0; u < NT; ++u) {
      const int cur = u & 1;
      const char* bX = (const char*)sX + (cur << 14);
      const char* bC = (const char*)sC + (cur << 14);
      i64x2 cf[4], xq[2];
#pragma unroll
      for (int q = 0; q < 4; ++q) {
        if (q == 0) {
#pragma unroll
          for (int n = 0; n < 4; ++n)
            cf[n] = *(const i64x2*)(bC + rcb + n * 1024 + sxor);
        }
#pragma unroll
        for (int mm = 0; mm < 2; ++mm)
          xq[mm] = *(const i64x2*)(bX + rxb + (2 * q + mm) * 1024 + sxor);
        if (q == 0 && u + 1 < NT) STAGE(cur ^ 1, 1, u + 1);
        if (q == 1 && u + 1 < NT) STAGE(cur ^ 1, 3, u + 1);
        if (q == 2 && u + 2 < NT) STAGE(cur, 0, u + 2);
        if (q == 3 && u + 2 < NT) STAGE(cur, 2, u + 2);
        __builtin_amdgcn_s_barrier();
        asm volatile("s_waitcnt lgkmcnt(0)" ::: "memory");
        __builtin_amdgcn_s_setprio(1);
        DOMFMA(q, 0);
        DOMFMA(q, 1);
        __builtin_amdgcn_s_setprio(0);
        if (q == 3) {
          if (u < NT - 2)
            asm volatile("s_waitcnt vmcnt(2)" ::: "memory");
          else if (u == NT - 2)
            asm volatile("s_waitcnt vmcnt(0)" ::: "memory");
        }
        __builtin_amdgcn_s_barrier();
        if (q == 3) __builtin_amdgcn_sched_barrier(0);
      }
    }
  }

  // epilogue: d = xsq + csq - 2*cross, clamp, exp; nt float4 stores.
  const int cgb = c0 + wc * 64 + (fq << 2);
  f32x4 csv[4];
#pragma unroll
  for (int n = 0; n < 4; ++n) csv[n] = *(const f32x4*)(csq + cgb + n * 16);
#pragma unroll
  for (int m = 0; m < 8; ++m) {
    const int xg = x0 + wr * 128 + m * 16 + fr;
    const float xs = xsq[xg];
    float* orow = out + (size_t)xg * MM + cgb;
#pragma unroll
    for (int n = 0; n < 4; ++n) {
      f32x4 v;
#pragma unroll
      for (int j = 0; j < 4; ++j) {
        float d = xs + csv[n][j] - 2.0f * acc[m][n][j];
        v[j] = __expf(-fmaxf(d, 0.0f));
      }
      __builtin_nontemporal_store(v, (f32x4*)(orow + n * 16));
    }
  }
}

// ---------------------------------------------------------------------------
// Fallback (ws too small): direct tiled fp32 distance kernel.
// ---------------------------------------------------------------------------
__global__ void rbf_naive(const float* __restrict__ x,
                          const float* __restrict__ c,
                          float* __restrict__ out) {
  __shared__ float sx[16][17], sc[16][17];
  const int tx = threadIdx.x, ty = threadIdx.y;
  const int row = blockIdx.y * 16 + ty;
  const int colb = blockIdx.x * 16;
  float d = 0.f;
  for (int k0 = 0; k0 < DD; k0 += 16) {
    sx[ty][tx] = x[(size_t)row * DD + k0 + tx];
    sc[ty][tx] = c[(size_t)(colb + ty) * DD + k0 + tx];
    __syncthreads();
#pragma unroll
    for (int k = 0; k < 16; ++k) {
      float diff = sx[ty][k] - sc[tx][k];
      d += diff * diff;
    }
    __syncthreads();
  }
  out[(size_t)row * MM + colb + tx] = __expf(-d);
}

extern "C" void kernel_launch(void* const* d_in, const int* in_sizes, int n_in,
                              void* d_out, int out_size, void* d_ws,
                              size_t ws_size, hipStream_t stream) {
  const float* x = (const float*)d_in[0];
  const float* c = (const float*)d_in[1];
  float* out = (float*)d_out;

  char* ws = (char*)d_ws;
  unsigned char* x8 = (unsigned char*)ws;
  unsigned char* c8 = x8 + (size_t)NN * DD;
  unsigned char* x8z = c8 + (size_t)MM * DD;
  float* xsq = (float*)(x8z + (size_t)NN * DD);
  float* csq = xsq + NN;
  const size_t need = (size_t)((char*)(csq + MM) - ws);

  if (ws_size < need) {
    dim3 grid(MM / 16, NN / 16), block(16, 16);
    rbf_naive<<<grid, block, 0, stream>>>(x, c, out);
    return;
  }

  prep_fp8<<<(NN + MM) / 4, 256, 0, stream>>>(x, c, x8, c8, x8z, xsq, csq);
  rbf_gemm<<<(NN / 256) * (MM / 256), 512, 0, stream>>>(x8, c8, x8z, xsq, csq, out);
}